// Round 1
// baseline (615.394 us; speedup 1.0000x reference)
//
#include <hip/hip_runtime.h>

#define T_ 2048
#define H_ 1024
#define E_ 8
#define I_ 2048

typedef short bf16x8 __attribute__((ext_vector_type(8)));
typedef float f32x4 __attribute__((ext_vector_type(4)));

__device__ __forceinline__ unsigned short f2bf(float f) {
  unsigned u = __builtin_bit_cast(unsigned, f);
  u += 0x7fffu + ((u >> 16) & 1u);   // RNE (finite inputs only)
  return (unsigned short)(u >> 16);
}

// ---------------- router: softmax + top2 + expert compaction ----------------
__global__ void router_kernel(const float* __restrict__ logits,
                              int* __restrict__ cnt,
                              int* __restrict__ plist,
                              float* __restrict__ wlist) {
  int t = blockIdx.x * blockDim.x + threadIdx.x;
  if (t >= T_) return;
  float l[E_];
#pragma unroll
  for (int e = 0; e < E_; ++e) l[e] = logits[t * E_ + e];
  int i0 = 0;
#pragma unroll
  for (int e = 1; e < E_; ++e) if (l[e] > l[i0]) i0 = e;
  int i1 = (i0 == 0) ? 1 : 0;
#pragma unroll
  for (int e = 0; e < E_; ++e) if (e != i0 && l[e] > l[i1]) i1 = e;
  // normalized top-2 softmax weights: w0 = 1/(1+exp(l1-l0))
  float w1 = 1.f / (1.f + __expf(l[i0] - l[i1]));
  float w0 = 1.f - w1;
  int s0 = atomicAdd(&cnt[i0], 1);
  plist[i0 * T_ + s0] = 2 * t;
  wlist[i0 * T_ + s0] = w0;
  int s1 = atomicAdd(&cnt[i1], 1);
  plist[i1 * T_ + s1] = 2 * t + 1;
  wlist[i1 * T_ + s1] = w1;
}

// ---------------- GEMM1: act = silu(hs*w13_g) * (hs*w13_u) * w -------------
// tiles: BM=128 rows (gathered tokens), BN=64 intermediate cols (x2: gate+up), BK=64
constexpr int BM = 128, BN = 64, BK = 64;

__global__ __launch_bounds__(256) void gemm1_kernel(
    const float* __restrict__ hs, const float* __restrict__ w13,
    const int* __restrict__ cnt, const int* __restrict__ plist,
    const float* __restrict__ wlist, unsigned short* __restrict__ act) {
  const int e = blockIdx.x >> 4;       // T_/BM == 16 m-tiles per expert
  const int mt = blockIdx.x & 15;
  const int M = cnt[e];
  if (mt * BM >= M) return;
  const int Mrem = M - mt * BM;
  const int n0 = blockIdx.y * BN;

  __shared__ __align__(16) unsigned short As[BM][BK];
  __shared__ __align__(16) unsigned short Bg[BN][BK];
  __shared__ __align__(16) unsigned short Bu[BN][BK];

  const int tid = threadIdx.x;
  const int lane = tid & 63;
  const int wid = tid >> 6;
  const int wm = (wid >> 1) * 64;   // wave row offset
  const int wn = (wid & 1) * 32;    // wave col offset

  // gather source rows for A staging (8 rows/thread)
  const float* aSrc[8];
#pragma unroll
  for (int j = 0; j < 8; ++j) {
    int r = (tid >> 4) + 16 * j;
    aSrc[j] = (r < Mrem) ? hs + (size_t)(plist[e * T_ + mt * BM + r] >> 1) * H_
                         : (const float*)nullptr;
  }
  const int ac4 = tid & 15;
  const float* w13g = w13 + ((size_t)e * 2 * I_ + n0) * H_;
  const float* w13u = w13 + ((size_t)e * 2 * I_ + I_ + n0) * H_;

  f32x4 accg[4][2] = {};
  f32x4 accu[4][2] = {};

  for (int k0 = 0; k0 < H_; k0 += BK) {
    // stage A (fp32 -> bf16)
#pragma unroll
    for (int j = 0; j < 8; ++j) {
      int r = (tid >> 4) + 16 * j;
      float4 v = make_float4(0.f, 0.f, 0.f, 0.f);
      if (aSrc[j]) v = *(const float4*)(aSrc[j] + k0 + ac4 * 4);
      ushort4 b;
      b.x = f2bf(v.x); b.y = f2bf(v.y); b.z = f2bf(v.z); b.w = f2bf(v.w);
      *(ushort4*)&As[r][ac4 * 4] = b;
    }
    // stage B gate+up (fp32 -> bf16); w13 is [i][h]: naturally N-major (B^T)
#pragma unroll
    for (int j = 0; j < 4; ++j) {
      int r = (tid >> 4) + 16 * j;
      float4 vg = *(const float4*)(w13g + (size_t)r * H_ + k0 + ac4 * 4);
      float4 vu = *(const float4*)(w13u + (size_t)r * H_ + k0 + ac4 * 4);
      ushort4 bg, bu;
      bg.x = f2bf(vg.x); bg.y = f2bf(vg.y); bg.z = f2bf(vg.z); bg.w = f2bf(vg.w);
      bu.x = f2bf(vu.x); bu.y = f2bf(vu.y); bu.z = f2bf(vu.z); bu.w = f2bf(vu.w);
      *(ushort4*)&Bg[r][ac4 * 4] = bg;
      *(ushort4*)&Bu[r][ac4 * 4] = bu;
    }
    __syncthreads();
#pragma unroll
    for (int ks = 0; ks < 2; ++ks) {
      bf16x8 af[4], bgf[2], buf2[2];
#pragma unroll
      for (int mi = 0; mi < 4; ++mi)
        af[mi] = *(const bf16x8*)&As[wm + mi * 16 + (lane & 15)][ks * 32 + (lane >> 4) * 8];
#pragma unroll
      for (int ni = 0; ni < 2; ++ni) {
        bgf[ni]  = *(const bf16x8*)&Bg[wn + ni * 16 + (lane & 15)][ks * 32 + (lane >> 4) * 8];
        buf2[ni] = *(const bf16x8*)&Bu[wn + ni * 16 + (lane & 15)][ks * 32 + (lane >> 4) * 8];
      }
#pragma unroll
      for (int mi = 0; mi < 4; ++mi)
#pragma unroll
        for (int ni = 0; ni < 2; ++ni) {
          accg[mi][ni] = __builtin_amdgcn_mfma_f32_16x16x32_bf16(af[mi], bgf[ni],  accg[mi][ni], 0, 0, 0);
          accu[mi][ni] = __builtin_amdgcn_mfma_f32_16x16x32_bf16(af[mi], buf2[ni], accu[mi][ni], 0, 0, 0);
        }
    }
    __syncthreads();
  }

  // epilogue: act = silu(g)*u*w, bf16 store. C/D: row=(lane>>4)*4+reg, col=lane&15
  const int lrow = lane >> 4, lcol = lane & 15;
#pragma unroll
  for (int mi = 0; mi < 4; ++mi) {
#pragma unroll
    for (int r = 0; r < 4; ++r) {
      int rl = wm + mi * 16 + lrow * 4 + r;
      if (rl < Mrem) {
        int rr = mt * BM + rl;
        int p = plist[e * T_ + rr];
        float w = wlist[e * T_ + rr];
        unsigned short* dst = act + (size_t)p * I_ + n0;
#pragma unroll
        for (int ni = 0; ni < 2; ++ni) {
          float g = accg[mi][ni][r];
          float u = accu[mi][ni][r];
          float a = (g / (1.f + __expf(-g))) * u * w;
          dst[wn + ni * 16 + lcol] = f2bf(a);
        }
      }
    }
  }
}

// ---------------- GEMM2: out[t,h] += act[p,:] . w2[e,h,:] ------------------
__global__ __launch_bounds__(256) void gemm2_kernel(
    const unsigned short* __restrict__ act, const float* __restrict__ w2,
    const int* __restrict__ cnt, const int* __restrict__ plist,
    float* __restrict__ out) {
  const int e = blockIdx.x >> 4;
  const int mt = blockIdx.x & 15;
  const int M = cnt[e];
  if (mt * BM >= M) return;
  const int Mrem = M - mt * BM;
  const int n0 = blockIdx.y * BN;  // h-tile

  __shared__ __align__(16) unsigned short As[BM][BK];
  __shared__ __align__(16) unsigned short Bs[BN][BK];

  const int tid = threadIdx.x;
  const int lane = tid & 63, wid = tid >> 6;
  const int wm = (wid >> 1) * 64, wn = (wid & 1) * 32;

  const unsigned short* aSrc[4];
#pragma unroll
  for (int j = 0; j < 4; ++j) {
    int r = (tid >> 3) + 32 * j;
    aSrc[j] = (r < Mrem) ? act + (size_t)plist[e * T_ + mt * BM + r] * I_
                         : (const unsigned short*)nullptr;
  }
  const int ac8 = tid & 7;
  const float* w2b = w2 + ((size_t)e * H_ + n0) * I_;  // w2 [h][i]: N-major (B^T)

  f32x4 acc[4][2] = {};

  for (int k0 = 0; k0 < I_; k0 += BK) {
    // stage A: act already bf16, 16B copies
#pragma unroll
    for (int j = 0; j < 4; ++j) {
      int r = (tid >> 3) + 32 * j;
      int4 v = make_int4(0, 0, 0, 0);
      if (aSrc[j]) v = *(const int4*)(aSrc[j] + k0 + ac8 * 8);
      *(int4*)&As[r][ac8 * 8] = v;
    }
    // stage B (fp32 -> bf16)
#pragma unroll
    for (int j = 0; j < 4; ++j) {
      int r = (tid >> 4) + 16 * j;
      float4 v = *(const float4*)(w2b + (size_t)r * I_ + k0 + (tid & 15) * 4);
      ushort4 b;
      b.x = f2bf(v.x); b.y = f2bf(v.y); b.z = f2bf(v.z); b.w = f2bf(v.w);
      *(ushort4*)&Bs[r][(tid & 15) * 4] = b;
    }
    __syncthreads();
#pragma unroll
    for (int ks = 0; ks < 2; ++ks) {
      bf16x8 af[4], bfb[2];
#pragma unroll
      for (int mi = 0; mi < 4; ++mi)
        af[mi] = *(const bf16x8*)&As[wm + mi * 16 + (lane & 15)][ks * 32 + (lane >> 4) * 8];
#pragma unroll
      for (int ni = 0; ni < 2; ++ni)
        bfb[ni] = *(const bf16x8*)&Bs[wn + ni * 16 + (lane & 15)][ks * 32 + (lane >> 4) * 8];
#pragma unroll
      for (int mi = 0; mi < 4; ++mi)
#pragma unroll
        for (int ni = 0; ni < 2; ++ni)
          acc[mi][ni] = __builtin_amdgcn_mfma_f32_16x16x32_bf16(af[mi], bfb[ni], acc[mi][ni], 0, 0, 0);
    }
    __syncthreads();
  }

  const int lrow = lane >> 4, lcol = lane & 15;
#pragma unroll
  for (int mi = 0; mi < 4; ++mi) {
#pragma unroll
    for (int r = 0; r < 4; ++r) {
      int rl = wm + mi * 16 + lrow * 4 + r;
      if (rl < Mrem) {
        int p = plist[e * T_ + mt * BM + rl];
        int t = p >> 1;
#pragma unroll
        for (int ni = 0; ni < 2; ++ni)
          atomicAdd(&out[(size_t)t * H_ + n0 + wn + ni * 16 + lcol], acc[mi][ni][r]);
      }
    }
  }
}

extern "C" void kernel_launch(void* const* d_in, const int* in_sizes, int n_in,
                              void* d_out, int out_size, void* d_ws, size_t ws_size,
                              hipStream_t stream) {
  const float* hs     = (const float*)d_in[0];
  const float* logits = (const float*)d_in[1];
  const float* w13    = (const float*)d_in[2];
  const float* w2     = (const float*)d_in[3];
  float* out = (float*)d_out;

  char* ws = (char*)d_ws;
  int*   cnt   = (int*)ws;                               // 8 ints (256B slot)
  int*   plist = (int*)(ws + 256);                       // E*T ints
  float* wlist = (float*)(ws + 256 + E_ * T_ * 4);       // E*T floats
  unsigned short* act = (unsigned short*)(ws + 256 + 2 * E_ * T_ * 4);  // 2*T x I bf16

  hipMemsetAsync(cnt, 0, 256, stream);
  hipMemsetAsync(d_out, 0, (size_t)out_size * sizeof(float), stream);

  router_kernel<<<T_ / 256, 256, 0, stream>>>(logits, cnt, plist, wlist);
  gemm1_kernel<<<dim3(E_ * (T_ / BM), I_ / BN), 256, 0, stream>>>(hs, w13, cnt, plist, wlist, act);
  gemm2_kernel<<<dim3(E_ * (T_ / BM), H_ / BN), 256, 0, stream>>>(act, w2, cnt, plist, out);
}

// Round 2
// 400.098 us; speedup vs baseline: 1.5381x; 1.5381x over previous
//
#include <hip/hip_runtime.h>

#define T_ 2048
#define H_ 1024
#define E_ 8
#define I_ 2048

typedef short bf16x8 __attribute__((ext_vector_type(8)));
typedef float f32x4 __attribute__((ext_vector_type(4)));
typedef unsigned short u16x8 __attribute__((ext_vector_type(8)));

__device__ __forceinline__ unsigned short f2bf(float f) {
  unsigned u = __builtin_bit_cast(unsigned, f);
  u += 0x7fffu + ((u >> 16) & 1u);   // RNE (finite inputs only)
  return (unsigned short)(u >> 16);
}

#define GLOAD_LDS16(g, l)                                                     \
  __builtin_amdgcn_global_load_lds(                                           \
      (const __attribute__((address_space(1))) unsigned int*)(g),             \
      (__attribute__((address_space(3))) unsigned int*)(l), 16, 0, 0)

// ---------------- fp32 -> bf16 streaming convert ---------------------------
__global__ __launch_bounds__(256) void cvt_kernel(const float* __restrict__ s,
                                                  unsigned short* __restrict__ d,
                                                  int n8) {
  int i = blockIdx.x * blockDim.x + threadIdx.x;
  if (i >= n8) return;
  const float4* s4 = (const float4*)s;
  float4 a = s4[2 * i], b = s4[2 * i + 1];
  u16x8 v;
  v[0] = f2bf(a.x); v[1] = f2bf(a.y); v[2] = f2bf(a.z); v[3] = f2bf(a.w);
  v[4] = f2bf(b.x); v[5] = f2bf(b.y); v[6] = f2bf(b.z); v[7] = f2bf(b.w);
  *(u16x8*)(d + (size_t)i * 8) = v;
}

// ---------------- router: softmax + top2 + expert compaction ----------------
__global__ void router_kernel(const float* __restrict__ logits,
                              int* __restrict__ cnt,
                              int* __restrict__ plist,
                              float* __restrict__ wlist) {
  int t = blockIdx.x * blockDim.x + threadIdx.x;
  if (t >= T_) return;
  float l[E_];
#pragma unroll
  for (int e = 0; e < E_; ++e) l[e] = logits[t * E_ + e];
  int i0 = 0;
#pragma unroll
  for (int e = 1; e < E_; ++e) if (l[e] > l[i0]) i0 = e;
  int i1 = (i0 == 0) ? 1 : 0;
#pragma unroll
  for (int e = 0; e < E_; ++e) if (e != i0 && l[e] > l[i1]) i1 = e;
  float w1 = 1.f / (1.f + __expf(l[i0] - l[i1]));
  float w0 = 1.f - w1;
  int s0 = atomicAdd(&cnt[i0], 1);
  plist[i0 * T_ + s0] = 2 * t;
  wlist[i0 * T_ + s0] = w0;
  int s1 = atomicAdd(&cnt[i1], 1);
  plist[i1 * T_ + s1] = 2 * t + 1;
  wlist[i1 * T_ + s1] = w1;
}

// ---------------- GEMM1: act = silu(hs*w13_g) * (hs*w13_u) * w -------------
// BM=128 gathered rows, BN=64 intermediate cols (gate+up), BK=64, 4 waves
__global__ __launch_bounds__(256) void gemm1_kernel(
    const unsigned short* __restrict__ hs_bf,
    const unsigned short* __restrict__ w13_bf,
    const int* __restrict__ cnt, const int* __restrict__ plist,
    const float* __restrict__ wlist, unsigned short* __restrict__ act) {
  const int e = blockIdx.x >> 4;
  const int mt = blockIdx.x & 15;
  const int M = cnt[e];
  if (mt * 128 >= M) return;
  const int Mrem = M - mt * 128;
  const int n0 = blockIdx.y * 64;

  __shared__ __align__(16) unsigned short As[128][64];
  __shared__ __align__(16) unsigned short Bg[64][64];
  __shared__ __align__(16) unsigned short Bu[64][64];

  const int tid = threadIdx.x;
  const int lane = tid & 63;
  const int wid = tid >> 6;
  const int wm = (wid >> 1) * 64;
  const int wn = (wid & 1) * 32;

  // staging sources (per-lane global addr; LDS dest is wave-uniform base)
  const unsigned short* aSrc[4];
#pragma unroll
  for (int i = 0; i < 4; ++i) {
    int r = wid * 32 + i * 8 + (lane >> 3);
    int idx = mt * 128 + ((r < Mrem) ? r : 0);
    int p = plist[e * T_ + idx];
    aSrc[i] = hs_bf + (size_t)(p >> 1) * H_ + (lane & 7) * 8;
  }
  const unsigned short* gSrc[2];
  const unsigned short* uSrc[2];
#pragma unroll
  for (int i = 0; i < 2; ++i) {
    int r = wid * 16 + i * 8 + (lane >> 3);
    gSrc[i] = w13_bf + ((size_t)e * (2 * I_) + n0 + r) * H_ + (lane & 7) * 8;
    uSrc[i] = gSrc[i] + (size_t)I_ * H_;
  }

  f32x4 accg[4][2] = {};
  f32x4 accu[4][2] = {};

  for (int k0 = 0; k0 < H_; k0 += 64) {
#pragma unroll
    for (int i = 0; i < 4; ++i)
      GLOAD_LDS16(aSrc[i] + k0, &As[wid * 32 + i * 8][0]);
#pragma unroll
    for (int i = 0; i < 2; ++i) {
      GLOAD_LDS16(gSrc[i] + k0, &Bg[wid * 16 + i * 8][0]);
      GLOAD_LDS16(uSrc[i] + k0, &Bu[wid * 16 + i * 8][0]);
    }
    __syncthreads();
#pragma unroll
    for (int ks = 0; ks < 2; ++ks) {
      bf16x8 af[4], bgf[2], buf2[2];
#pragma unroll
      for (int mi = 0; mi < 4; ++mi)
        af[mi] = *(const bf16x8*)&As[wm + mi * 16 + (lane & 15)][ks * 32 + (lane >> 4) * 8];
#pragma unroll
      for (int ni = 0; ni < 2; ++ni) {
        bgf[ni]  = *(const bf16x8*)&Bg[wn + ni * 16 + (lane & 15)][ks * 32 + (lane >> 4) * 8];
        buf2[ni] = *(const bf16x8*)&Bu[wn + ni * 16 + (lane & 15)][ks * 32 + (lane >> 4) * 8];
      }
#pragma unroll
      for (int mi = 0; mi < 4; ++mi)
#pragma unroll
        for (int ni = 0; ni < 2; ++ni) {
          accg[mi][ni] = __builtin_amdgcn_mfma_f32_16x16x32_bf16(af[mi], bgf[ni],  accg[mi][ni], 0, 0, 0);
          accu[mi][ni] = __builtin_amdgcn_mfma_f32_16x16x32_bf16(af[mi], buf2[ni], accu[mi][ni], 0, 0, 0);
        }
    }
    __syncthreads();
  }

  const int lrow = lane >> 4, lcol = lane & 15;
#pragma unroll
  for (int mi = 0; mi < 4; ++mi) {
#pragma unroll
    for (int r = 0; r < 4; ++r) {
      int rl = wm + mi * 16 + lrow * 4 + r;
      if (rl < Mrem) {
        int rr = mt * 128 + rl;
        int p = plist[e * T_ + rr];
        float w = wlist[e * T_ + rr];
        unsigned short* dst = act + (size_t)p * I_ + n0;
#pragma unroll
        for (int ni = 0; ni < 2; ++ni) {
          float g = accg[mi][ni][r];
          float u = accu[mi][ni][r];
          float a = (g / (1.f + __expf(-g))) * u * w;
          dst[wn + ni * 16 + lcol] = f2bf(a);
        }
      }
    }
  }
}

// ---------------- GEMM2: out[t,h] += act[p,:] . w2[e,h,:] ------------------
// BM=128 gathered act rows, BN=128 h cols, BK=64, 4 waves
__global__ __launch_bounds__(256) void gemm2_kernel(
    const unsigned short* __restrict__ act,
    const unsigned short* __restrict__ w2_bf,
    const int* __restrict__ cnt, const int* __restrict__ plist,
    float* __restrict__ out) {
  const int e = blockIdx.x >> 4;
  const int mt = blockIdx.x & 15;
  const int M = cnt[e];
  if (mt * 128 >= M) return;
  const int Mrem = M - mt * 128;
  const int n0 = blockIdx.y * 128;

  __shared__ __align__(16) unsigned short As[128][64];
  __shared__ __align__(16) unsigned short Bs[128][64];

  const int tid = threadIdx.x;
  const int lane = tid & 63;
  const int wid = tid >> 6;
  const int wm = (wid >> 1) * 64;
  const int wn = (wid & 1) * 64;

  const unsigned short* aSrc[4];
  const unsigned short* bSrc[4];
#pragma unroll
  for (int i = 0; i < 4; ++i) {
    int r = wid * 32 + i * 8 + (lane >> 3);
    int idx = mt * 128 + ((r < Mrem) ? r : 0);
    int p = plist[e * T_ + idx];
    aSrc[i] = act + (size_t)p * I_ + (lane & 7) * 8;
    bSrc[i] = w2_bf + ((size_t)e * H_ + n0 + r) * I_ + (lane & 7) * 8;
  }

  f32x4 acc[4][4] = {};

  for (int k0 = 0; k0 < I_; k0 += 64) {
#pragma unroll
    for (int i = 0; i < 4; ++i) {
      GLOAD_LDS16(aSrc[i] + k0, &As[wid * 32 + i * 8][0]);
      GLOAD_LDS16(bSrc[i] + k0, &Bs[wid * 32 + i * 8][0]);
    }
    __syncthreads();
#pragma unroll
    for (int ks = 0; ks < 2; ++ks) {
      bf16x8 af[4], bfb[4];
#pragma unroll
      for (int mi = 0; mi < 4; ++mi)
        af[mi] = *(const bf16x8*)&As[wm + mi * 16 + (lane & 15)][ks * 32 + (lane >> 4) * 8];
#pragma unroll
      for (int ni = 0; ni < 4; ++ni)
        bfb[ni] = *(const bf16x8*)&Bs[wn + ni * 16 + (lane & 15)][ks * 32 + (lane >> 4) * 8];
#pragma unroll
      for (int mi = 0; mi < 4; ++mi)
#pragma unroll
        for (int ni = 0; ni < 4; ++ni)
          acc[mi][ni] = __builtin_amdgcn_mfma_f32_16x16x32_bf16(af[mi], bfb[ni], acc[mi][ni], 0, 0, 0);
    }
    __syncthreads();
  }

  const int lrow = lane >> 4, lcol = lane & 15;
#pragma unroll
  for (int mi = 0; mi < 4; ++mi) {
#pragma unroll
    for (int r = 0; r < 4; ++r) {
      int rl = wm + mi * 16 + lrow * 4 + r;
      if (rl < Mrem) {
        int p = plist[e * T_ + mt * 128 + rl];
        int t = p >> 1;
#pragma unroll
        for (int ni = 0; ni < 4; ++ni)
          atomicAdd(&out[(size_t)t * H_ + n0 + wn + ni * 16 + lcol], acc[mi][ni][r]);
      }
    }
  }
}

extern "C" void kernel_launch(void* const* d_in, const int* in_sizes, int n_in,
                              void* d_out, int out_size, void* d_ws, size_t ws_size,
                              hipStream_t stream) {
  const float* hs     = (const float*)d_in[0];
  const float* logits = (const float*)d_in[1];
  const float* w13    = (const float*)d_in[2];
  const float* w2     = (const float*)d_in[3];
  float* out = (float*)d_out;

  char* ws = (char*)d_ws;
  size_t off = 0;
  int* cnt = (int*)(ws + off);           off += 256;
  int* plist = (int*)(ws + off);         off += (size_t)E_ * T_ * 4;
  float* wlist = (float*)(ws + off);     off += (size_t)E_ * T_ * 4;
  unsigned short* act = (unsigned short*)(ws + off);    off += (size_t)2 * T_ * I_ * 2;
  unsigned short* hs_bf = (unsigned short*)(ws + off);  off += (size_t)T_ * H_ * 2;
  unsigned short* w13_bf = (unsigned short*)(ws + off); off += (size_t)E_ * 2 * I_ * H_ * 2;
  unsigned short* w2_bf = (unsigned short*)(ws + off);  off += (size_t)E_ * H_ * I_ * 2;
  // total ~122 MB

  hipMemsetAsync(cnt, 0, 256, stream);
  hipMemsetAsync(d_out, 0, (size_t)out_size * sizeof(float), stream);

  const int nHs  = T_ * H_ / 8;
  const int nW13 = E_ * 2 * I_ * H_ / 8;
  const int nW2  = E_ * H_ * I_ / 8;
  cvt_kernel<<<(nHs + 255) / 256, 256, 0, stream>>>(hs, hs_bf, nHs);
  cvt_kernel<<<(nW13 + 255) / 256, 256, 0, stream>>>(w13, w13_bf, nW13);
  cvt_kernel<<<(nW2 + 255) / 256, 256, 0, stream>>>(w2, w2_bf, nW2);
  router_kernel<<<T_ / 256, 256, 0, stream>>>(logits, cnt, plist, wlist);

  gemm1_kernel<<<dim3(E_ * 16, I_ / 64), 256, 0, stream>>>(hs_bf, w13_bf, cnt, plist, wlist, act);
  gemm2_kernel<<<dim3(E_ * 16, H_ / 128), 256, 0, stream>>>(act, w2_bf, cnt, plist, out);
}

// Round 3
// 398.066 us; speedup vs baseline: 1.5460x; 1.0051x over previous
//
#include <hip/hip_runtime.h>

#define T_ 2048
#define H_ 1024
#define E_ 8
#define I_ 2048

typedef short bf16x8 __attribute__((ext_vector_type(8)));
typedef float f32x4 __attribute__((ext_vector_type(4)));
typedef unsigned short u16x8 __attribute__((ext_vector_type(8)));

__device__ __forceinline__ unsigned short f2bf(float f) {
  unsigned u = __builtin_bit_cast(unsigned, f);
  u += 0x7fffu + ((u >> 16) & 1u);   // RNE (finite inputs only)
  return (unsigned short)(u >> 16);
}

#define GLOAD_LDS16(g, l)                                                     \
  __builtin_amdgcn_global_load_lds(                                           \
      (const __attribute__((address_space(1))) unsigned int*)(g),             \
      (__attribute__((address_space(3))) unsigned int*)(l), 16, 0, 0)

// ---------------- fp32 -> bf16 streaming convert ---------------------------
__global__ __launch_bounds__(256) void cvt_kernel(const float* __restrict__ s,
                                                  unsigned short* __restrict__ d,
                                                  int n8) {
  int i = blockIdx.x * blockDim.x + threadIdx.x;
  if (i >= n8) return;
  const float4* s4 = (const float4*)s;
  float4 a = s4[2 * i], b = s4[2 * i + 1];
  u16x8 v;
  v[0] = f2bf(a.x); v[1] = f2bf(a.y); v[2] = f2bf(a.z); v[3] = f2bf(a.w);
  v[4] = f2bf(b.x); v[5] = f2bf(b.y); v[6] = f2bf(b.z); v[7] = f2bf(b.w);
  *(u16x8*)(d + (size_t)i * 8) = v;
}

// ---------------- router: softmax + top2 + expert compaction ----------------
__global__ void router_kernel(const float* __restrict__ logits,
                              int* __restrict__ cnt,
                              int* __restrict__ plist,
                              float* __restrict__ wlist) {
  int t = blockIdx.x * blockDim.x + threadIdx.x;
  if (t >= T_) return;
  float l[E_];
#pragma unroll
  for (int e = 0; e < E_; ++e) l[e] = logits[t * E_ + e];
  int i0 = 0;
#pragma unroll
  for (int e = 1; e < E_; ++e) if (l[e] > l[i0]) i0 = e;
  int i1 = (i0 == 0) ? 1 : 0;
#pragma unroll
  for (int e = 0; e < E_; ++e) if (e != i0 && l[e] > l[i1]) i1 = e;
  float w1 = 1.f / (1.f + __expf(l[i0] - l[i1]));
  float w0 = 1.f - w1;
  int s0 = atomicAdd(&cnt[i0], 1);
  plist[i0 * T_ + s0] = 2 * t;
  wlist[i0 * T_ + s0] = w0;
  int s1 = atomicAdd(&cnt[i1], 1);
  plist[i1 * T_ + s1] = 2 * t + 1;
  wlist[i1 * T_ + s1] = w1;
}

// ---------------- GEMM1: act = silu(hs*w13_g) * (hs*w13_u) * w -------------
// BM=128, BN=64 i-cols (gate+up), BK=64, 4 waves, 2-phase dbuf + counted vmcnt
__global__ __launch_bounds__(256) void gemm1_kernel(
    const unsigned short* __restrict__ hs_bf,
    const unsigned short* __restrict__ w13_bf,
    const int* __restrict__ cnt, const int* __restrict__ plist,
    const float* __restrict__ wlist, unsigned short* __restrict__ act) {
  const int e = blockIdx.x >> 4;
  const int mt = blockIdx.x & 15;
  const int M = cnt[e];
  if (mt * 128 >= M) return;
  const int Mrem = M - mt * 128;
  const int n0 = blockIdx.y * 64;

  __shared__ __align__(16) unsigned short As[2][128][64];
  __shared__ __align__(16) unsigned short Bg[2][64][64];
  __shared__ __align__(16) unsigned short Bu[2][64][64];

  const int tid = threadIdx.x;
  const int lane = tid & 63;
  const int wid = tid >> 6;
  const int wm = (wid >> 1) * 64;
  const int wn = (wid & 1) * 32;

  // staging sources (per-lane global addr; LDS dest wave-uniform + lane*16B)
  const unsigned short* aSrc[4];
#pragma unroll
  for (int i = 0; i < 4; ++i) {
    int r = wid * 32 + i * 8 + (lane >> 3);
    int idx = mt * 128 + ((r < Mrem) ? r : 0);
    int p = plist[e * T_ + idx];
    aSrc[i] = hs_bf + (size_t)(p >> 1) * H_ + (lane & 7) * 8;
  }
  const unsigned short* gSrc[2];
  const unsigned short* uSrc[2];
#pragma unroll
  for (int i = 0; i < 2; ++i) {
    int r = wid * 16 + i * 8 + (lane >> 3);
    gSrc[i] = w13_bf + ((size_t)e * (2 * I_) + n0 + r) * H_ + (lane & 7) * 8;
    uSrc[i] = gSrc[i] + (size_t)I_ * H_;
  }

  // 8 gload_lds per wave per stage
#define STAGE1(buf, k0)                                                       \
  do {                                                                        \
    _Pragma("unroll") for (int i = 0; i < 4; ++i)                             \
        GLOAD_LDS16(aSrc[i] + (k0), &As[buf][wid * 32 + i * 8][0]);           \
    _Pragma("unroll") for (int i = 0; i < 2; ++i) {                           \
      GLOAD_LDS16(gSrc[i] + (k0), &Bg[buf][wid * 16 + i * 8][0]);             \
      GLOAD_LDS16(uSrc[i] + (k0), &Bu[buf][wid * 16 + i * 8][0]);             \
    }                                                                         \
  } while (0)

  f32x4 accg[4][2] = {};
  f32x4 accu[4][2] = {};

  STAGE1(0, 0);
#pragma unroll 1
  for (int k0 = 0; k0 < H_; k0 += 64) {
    const int cur = (k0 >> 6) & 1;
    if (k0 + 64 < H_) {
      STAGE1(cur ^ 1, k0 + 64);
      asm volatile("s_waitcnt vmcnt(8)" ::: "memory");
    } else {
      asm volatile("s_waitcnt vmcnt(0)" ::: "memory");
    }
    __builtin_amdgcn_s_barrier();
    __builtin_amdgcn_sched_barrier(0);
#pragma unroll
    for (int ks = 0; ks < 2; ++ks) {
      bf16x8 af[4], bgf[2], buf2[2];
#pragma unroll
      for (int mi = 0; mi < 4; ++mi)
        af[mi] = *(const bf16x8*)&As[cur][wm + mi * 16 + (lane & 15)][ks * 32 + (lane >> 4) * 8];
#pragma unroll
      for (int ni = 0; ni < 2; ++ni) {
        bgf[ni]  = *(const bf16x8*)&Bg[cur][wn + ni * 16 + (lane & 15)][ks * 32 + (lane >> 4) * 8];
        buf2[ni] = *(const bf16x8*)&Bu[cur][wn + ni * 16 + (lane & 15)][ks * 32 + (lane >> 4) * 8];
      }
#pragma unroll
      for (int mi = 0; mi < 4; ++mi)
#pragma unroll
        for (int ni = 0; ni < 2; ++ni) {
          accg[mi][ni] = __builtin_amdgcn_mfma_f32_16x16x32_bf16(af[mi], bgf[ni],  accg[mi][ni], 0, 0, 0);
          accu[mi][ni] = __builtin_amdgcn_mfma_f32_16x16x32_bf16(af[mi], buf2[ni], accu[mi][ni], 0, 0, 0);
        }
    }
    __builtin_amdgcn_sched_barrier(0);
    __builtin_amdgcn_s_barrier();
  }

  const int lrow = lane >> 4, lcol = lane & 15;
#pragma unroll
  for (int mi = 0; mi < 4; ++mi) {
#pragma unroll
    for (int r = 0; r < 4; ++r) {
      int rl = wm + mi * 16 + lrow * 4 + r;
      if (rl < Mrem) {
        int rr = mt * 128 + rl;
        int p = plist[e * T_ + rr];
        float w = wlist[e * T_ + rr];
        unsigned short* dst = act + (size_t)p * I_ + n0;
#pragma unroll
        for (int ni = 0; ni < 2; ++ni) {
          float g = accg[mi][ni][r];
          float u = accu[mi][ni][r];
          float a = (g / (1.f + __expf(-g))) * u * w;
          dst[wn + ni * 16 + lcol] = f2bf(a);
        }
      }
    }
  }
}

// ---------------- GEMM2: out[t,h] += act[p,:] . w2[e,h,:] ------------------
// BM=128, BN=128 h-cols, BK=64, 4 waves, 2-phase dbuf + counted vmcnt
__global__ __launch_bounds__(256) void gemm2_kernel(
    const unsigned short* __restrict__ act,
    const unsigned short* __restrict__ w2_bf,
    const int* __restrict__ cnt, const int* __restrict__ plist,
    float* __restrict__ out) {
  const int e = blockIdx.x >> 4;
  const int mt = blockIdx.x & 15;
  const int M = cnt[e];
  if (mt * 128 >= M) return;
  const int Mrem = M - mt * 128;
  const int n0 = blockIdx.y * 128;

  __shared__ __align__(16) unsigned short As[2][128][64];
  __shared__ __align__(16) unsigned short Bs[2][128][64];

  const int tid = threadIdx.x;
  const int lane = tid & 63;
  const int wid = tid >> 6;
  const int wm = (wid >> 1) * 64;
  const int wn = (wid & 1) * 64;

  const unsigned short* aSrc[4];
  const unsigned short* bSrc[4];
#pragma unroll
  for (int i = 0; i < 4; ++i) {
    int r = wid * 32 + i * 8 + (lane >> 3);
    int idx = mt * 128 + ((r < Mrem) ? r : 0);
    int p = plist[e * T_ + idx];
    aSrc[i] = act + (size_t)p * I_ + (lane & 7) * 8;
    bSrc[i] = w2_bf + ((size_t)e * H_ + n0 + r) * I_ + (lane & 7) * 8;
  }

#define STAGE2(buf, k0)                                                       \
  do {                                                                        \
    _Pragma("unroll") for (int i = 0; i < 4; ++i) {                           \
      GLOAD_LDS16(aSrc[i] + (k0), &As[buf][wid * 32 + i * 8][0]);             \
      GLOAD_LDS16(bSrc[i] + (k0), &Bs[buf][wid * 32 + i * 8][0]);             \
    }                                                                         \
  } while (0)

  f32x4 acc[4][4] = {};

  STAGE2(0, 0);
#pragma unroll 1
  for (int k0 = 0; k0 < I_; k0 += 64) {
    const int cur = (k0 >> 6) & 1;
    if (k0 + 64 < I_) {
      STAGE2(cur ^ 1, k0 + 64);
      asm volatile("s_waitcnt vmcnt(8)" ::: "memory");
    } else {
      asm volatile("s_waitcnt vmcnt(0)" ::: "memory");
    }
    __builtin_amdgcn_s_barrier();
    __builtin_amdgcn_sched_barrier(0);
#pragma unroll
    for (int ks = 0; ks < 2; ++ks) {
      bf16x8 af[4], bfb[4];
#pragma unroll
      for (int mi = 0; mi < 4; ++mi)
        af[mi] = *(const bf16x8*)&As[cur][wm + mi * 16 + (lane & 15)][ks * 32 + (lane >> 4) * 8];
#pragma unroll
      for (int ni = 0; ni < 4; ++ni)
        bfb[ni] = *(const bf16x8*)&Bs[cur][wn + ni * 16 + (lane & 15)][ks * 32 + (lane >> 4) * 8];
#pragma unroll
      for (int mi = 0; mi < 4; ++mi)
#pragma unroll
        for (int ni = 0; ni < 4; ++ni)
          acc[mi][ni] = __builtin_amdgcn_mfma_f32_16x16x32_bf16(af[mi], bfb[ni], acc[mi][ni], 0, 0, 0);
    }
    __builtin_amdgcn_sched_barrier(0);
    __builtin_amdgcn_s_barrier();
  }

  const int lrow = lane >> 4, lcol = lane & 15;
#pragma unroll
  for (int mi = 0; mi < 4; ++mi) {
#pragma unroll
    for (int r = 0; r < 4; ++r) {
      int rl = wm + mi * 16 + lrow * 4 + r;
      if (rl < Mrem) {
        int p = plist[e * T_ + mt * 128 + rl];
        int t = p >> 1;
#pragma unroll
        for (int ni = 0; ni < 4; ++ni)
          atomicAdd(&out[(size_t)t * H_ + n0 + wn + ni * 16 + lcol], acc[mi][ni][r]);
      }
    }
  }
}

extern "C" void kernel_launch(void* const* d_in, const int* in_sizes, int n_in,
                              void* d_out, int out_size, void* d_ws, size_t ws_size,
                              hipStream_t stream) {
  const float* hs     = (const float*)d_in[0];
  const float* logits = (const float*)d_in[1];
  const float* w13    = (const float*)d_in[2];
  const float* w2     = (const float*)d_in[3];
  float* out = (float*)d_out;

  char* ws = (char*)d_ws;
  size_t off = 0;
  int* cnt = (int*)(ws + off);           off += 256;
  int* plist = (int*)(ws + off);         off += (size_t)E_ * T_ * 4;
  float* wlist = (float*)(ws + off);     off += (size_t)E_ * T_ * 4;
  unsigned short* act = (unsigned short*)(ws + off);    off += (size_t)2 * T_ * I_ * 2;
  unsigned short* hs_bf = (unsigned short*)(ws + off);  off += (size_t)T_ * H_ * 2;
  unsigned short* w13_bf = (unsigned short*)(ws + off); off += (size_t)E_ * 2 * I_ * H_ * 2;
  unsigned short* w2_bf = (unsigned short*)(ws + off);  off += (size_t)E_ * H_ * I_ * 2;
  // total ~122 MB

  hipMemsetAsync(cnt, 0, 256, stream);
  hipMemsetAsync(d_out, 0, (size_t)out_size * sizeof(float), stream);

  const int nHs  = T_ * H_ / 8;
  const int nW13 = E_ * 2 * I_ * H_ / 8;
  const int nW2  = E_ * H_ * I_ / 8;
  cvt_kernel<<<(nHs + 255) / 256, 256, 0, stream>>>(hs, hs_bf, nHs);
  cvt_kernel<<<(nW13 + 255) / 256, 256, 0, stream>>>(w13, w13_bf, nW13);
  cvt_kernel<<<(nW2 + 255) / 256, 256, 0, stream>>>(w2, w2_bf, nW2);
  router_kernel<<<T_ / 256, 256, 0, stream>>>(logits, cnt, plist, wlist);

  gemm1_kernel<<<dim3(E_ * 16, I_ / 64), 256, 0, stream>>>(hs_bf, w13_bf, cnt, plist, wlist, act);
  gemm2_kernel<<<dim3(E_ * 16, H_ / 128), 256, 0, stream>>>(act, w2_bf, cnt, plist, out);
}

// Round 4
// 356.698 us; speedup vs baseline: 1.7253x; 1.1160x over previous
//
#include <hip/hip_runtime.h>

#define T_ 2048
#define H_ 1024
#define E_ 8
#define I_ 2048

typedef short bf16x8 __attribute__((ext_vector_type(8)));
typedef float f32x4 __attribute__((ext_vector_type(4)));
typedef unsigned short u16x8 __attribute__((ext_vector_type(8)));

__device__ __forceinline__ unsigned short f2bf(float f) {
  unsigned u = __builtin_bit_cast(unsigned, f);
  u += 0x7fffu + ((u >> 16) & 1u);   // RNE (finite inputs only)
  return (unsigned short)(u >> 16);
}

#define GLOAD_LDS16(g, l)                                                     \
  __builtin_amdgcn_global_load_lds(                                           \
      (const __attribute__((address_space(1))) unsigned int*)(g),             \
      (__attribute__((address_space(3))) unsigned int*)(l), 16, 0, 0)

// ---------------- fp32 -> bf16 linear convert (hs) -------------------------
__global__ __launch_bounds__(256) void cvt_kernel(const float* __restrict__ s,
                                                  unsigned short* __restrict__ d,
                                                  int n8) {
  int i = blockIdx.x * blockDim.x + threadIdx.x;
  if (i >= n8) return;
  const float4* s4 = (const float4*)s;
  float4 a = s4[2 * i], b = s4[2 * i + 1];
  u16x8 v;
  v[0] = f2bf(a.x); v[1] = f2bf(a.y); v[2] = f2bf(a.z); v[3] = f2bf(a.w);
  v[4] = f2bf(b.x); v[5] = f2bf(b.y); v[6] = f2bf(b.z); v[7] = f2bf(b.w);
  *(u16x8*)(d + (size_t)i * 8) = v;
}

// ---------------- pack w13 -> [e][nt=32][kt=16][r=128][k=64] bf16, swizzled -
// tile rows: r<64 = gate rows nt*64+r ; r>=64 = up rows I_+nt*64+(r-64)
// swizzle baked: element k stored at chunk (k>>3)^(r&7), offset k&7
__global__ __launch_bounds__(256) void pack_w13(const float* __restrict__ src,
                                                unsigned short* __restrict__ dst) {
  const int b = blockIdx.x;            // ((e*32+nt)*16+kt), kt fastest
  const int kt = b & 15;
  const int nt = (b >> 4) & 31;
  const int e  = b >> 9;
  const float* gbase = src + ((size_t)e * 2 * I_ + nt * 64) * H_ + kt * 64;
  const float* ubase = gbase + (size_t)I_ * H_;
  unsigned short* out = dst + (size_t)b * (128 * 64);
  const int c4 = (threadIdx.x & 15) * 4;   // k offset (floats), {0,4,..,60}
  const int r0 = threadIdx.x >> 4;
#pragma unroll
  for (int rp = 0; rp < 8; ++rp) {
    int r = rp * 16 + r0;
    const float* s = ((r < 64) ? (gbase + (size_t)r * H_)
                               : (ubase + (size_t)(r - 64) * H_)) + c4;
    float4 v = *(const float4*)s;
    ushort4 o;
    o.x = f2bf(v.x); o.y = f2bf(v.y); o.z = f2bf(v.z); o.w = f2bf(v.w);
    int kk = (((c4 >> 3) ^ (r & 7)) << 3) + (c4 & 7);
    *(ushort4*)(out + r * 64 + kk) = o;
  }
}

// ---------------- pack w2 -> [e][nt=8][kt=32][r=128][k=64] bf16, swizzled ---
__global__ __launch_bounds__(256) void pack_w2(const float* __restrict__ src,
                                               unsigned short* __restrict__ dst) {
  const int b = blockIdx.x;            // ((e*8+nt)*32+kt), kt fastest
  const int kt = b & 31;
  const int nt = (b >> 5) & 7;
  const int e  = b >> 8;
  const float* base = src + ((size_t)e * H_ + nt * 128) * I_ + kt * 64;
  unsigned short* out = dst + (size_t)b * (128 * 64);
  const int c4 = (threadIdx.x & 15) * 4;
  const int r0 = threadIdx.x >> 4;
#pragma unroll
  for (int rp = 0; rp < 8; ++rp) {
    int r = rp * 16 + r0;
    const float* s = base + (size_t)r * I_ + c4;
    float4 v = *(const float4*)s;
    ushort4 o;
    o.x = f2bf(v.x); o.y = f2bf(v.y); o.z = f2bf(v.z); o.w = f2bf(v.w);
    int kk = (((c4 >> 3) ^ (r & 7)) << 3) + (c4 & 7);
    *(ushort4*)(out + r * 64 + kk) = o;
  }
}

// ---------------- router: softmax + top2 + expert compaction ----------------
__global__ void router_kernel(const float* __restrict__ logits,
                              int* __restrict__ cnt,
                              int* __restrict__ plist,
                              float* __restrict__ wlist) {
  int t = blockIdx.x * blockDim.x + threadIdx.x;
  if (t >= T_) return;
  float l[E_];
#pragma unroll
  for (int e = 0; e < E_; ++e) l[e] = logits[t * E_ + e];
  int i0 = 0;
#pragma unroll
  for (int e = 1; e < E_; ++e) if (l[e] > l[i0]) i0 = e;
  int i1 = (i0 == 0) ? 1 : 0;
#pragma unroll
  for (int e = 0; e < E_; ++e) if (e != i0 && l[e] > l[i1]) i1 = e;
  float w1 = 1.f / (1.f + __expf(l[i0] - l[i1]));
  float w0 = 1.f - w1;
  int s0 = atomicAdd(&cnt[i0], 1);
  plist[i0 * T_ + s0] = 2 * t;
  wlist[i0 * T_ + s0] = w0;
  int s1 = atomicAdd(&cnt[i1], 1);
  plist[i1 * T_ + s1] = 2 * t + 1;
  wlist[i1 * T_ + s1] = w1;
}

// ---------------- GEMM1: act = silu(hs*w13_g)*(hs*w13_u)*w ------------------
// BM=128, BN=64 (gate+up pair), BK=64, packed+swizzled B tiles
__global__ __launch_bounds__(256) void gemm1_kernel(
    const unsigned short* __restrict__ hs_bf,
    const unsigned short* __restrict__ w13p,
    const int* __restrict__ cnt, const int* __restrict__ plist,
    const float* __restrict__ wlist, unsigned short* __restrict__ act) {
  const int e = blockIdx.x >> 4;
  const int mt = blockIdx.x & 15;
  const int M = cnt[e];
  if (mt * 128 >= M) return;
  const int Mrem = M - mt * 128;
  const int nt = blockIdx.y;
  const int n0 = nt * 64;

  __shared__ __align__(16) unsigned short As[2][128][64];
  __shared__ __align__(16) unsigned short Bs[2][128][64];

  const int tid = threadIdx.x;
  const int lane = tid & 63;
  const int wid = tid >> 6;
  const int wm = (wid >> 1) * 64;
  const int wn = (wid & 1) * 32;

  const unsigned short* aSrc[4];
#pragma unroll
  for (int i = 0; i < 4; ++i) {
    int r = wid * 32 + i * 8 + (lane >> 3);
    int idx = mt * 128 + ((r < Mrem) ? r : 0);
    int p = plist[e * T_ + idx];
    aSrc[i] = hs_bf + (size_t)(p >> 1) * H_ + (lane & 7) * 8;
  }
  const unsigned short* bT = w13p + (size_t)((e * 32 + nt) * 16) * 8192;
  const unsigned short* bSrc[4];
#pragma unroll
  for (int i = 0; i < 4; ++i)
    bSrc[i] = bT + (wid * 32 + i * 8 + (lane >> 3)) * 64 + (lane & 7) * 8;

#define STAGE1(buf, kt)                                                       \
  do {                                                                        \
    _Pragma("unroll") for (int i = 0; i < 4; ++i)                             \
        GLOAD_LDS16(aSrc[i] + (kt) * 64, &As[buf][wid * 32 + i * 8][0]);      \
    _Pragma("unroll") for (int i = 0; i < 4; ++i)                             \
        GLOAD_LDS16(bSrc[i] + (kt) * 8192, &Bs[buf][wid * 32 + i * 8][0]);    \
  } while (0)

  f32x4 accg[4][2] = {};
  f32x4 accu[4][2] = {};

  STAGE1(0, 0);
#pragma unroll 1
  for (int kt = 0; kt < 16; ++kt) {
    const int cur = kt & 1;
    if (kt + 1 < 16) {
      STAGE1(cur ^ 1, kt + 1);
      asm volatile("s_waitcnt vmcnt(8)" ::: "memory");
    } else {
      asm volatile("s_waitcnt vmcnt(0)" ::: "memory");
    }
    __builtin_amdgcn_s_barrier();
    __builtin_amdgcn_sched_barrier(0);
#pragma unroll
    for (int ks = 0; ks < 2; ++ks) {
      bf16x8 af[4], bgf[2], buf2[2];
#pragma unroll
      for (int mi = 0; mi < 4; ++mi)
        af[mi] = *(const bf16x8*)&As[cur][wm + mi * 16 + (lane & 15)][ks * 32 + (lane >> 4) * 8];
      const int cbase = ks * 4 + (lane >> 4);
#pragma unroll
      for (int ni = 0; ni < 2; ++ni) {
        int rr = wn + ni * 16 + (lane & 15);
        int cc = (cbase ^ (rr & 7)) << 3;
        bgf[ni]  = *(const bf16x8*)&Bs[cur][rr][cc];
        buf2[ni] = *(const bf16x8*)&Bs[cur][rr + 64][cc];
      }
#pragma unroll
      for (int mi = 0; mi < 4; ++mi)
#pragma unroll
        for (int ni = 0; ni < 2; ++ni) {
          accg[mi][ni] = __builtin_amdgcn_mfma_f32_16x16x32_bf16(af[mi], bgf[ni],  accg[mi][ni], 0, 0, 0);
          accu[mi][ni] = __builtin_amdgcn_mfma_f32_16x16x32_bf16(af[mi], buf2[ni], accu[mi][ni], 0, 0, 0);
        }
    }
    __builtin_amdgcn_sched_barrier(0);
    __builtin_amdgcn_s_barrier();
  }

  const int lrow = lane >> 4, lcol = lane & 15;
#pragma unroll
  for (int mi = 0; mi < 4; ++mi) {
#pragma unroll
    for (int r = 0; r < 4; ++r) {
      int rl = wm + mi * 16 + lrow * 4 + r;
      if (rl < Mrem) {
        int rr = mt * 128 + rl;
        int p = plist[e * T_ + rr];
        float w = wlist[e * T_ + rr];
        unsigned short* dst = act + (size_t)p * I_ + n0;
#pragma unroll
        for (int ni = 0; ni < 2; ++ni) {
          float g = accg[mi][ni][r];
          float u = accu[mi][ni][r];
          float a = (g / (1.f + __expf(-g))) * u * w;
          dst[wn + ni * 16 + lcol] = f2bf(a);
        }
      }
    }
  }
}

// ---------------- GEMM2: out[t,h] += act[p,:] . w2[e,h,:] -------------------
// BM=128, BN=128, BK=64, packed+swizzled B tiles
__global__ __launch_bounds__(256) void gemm2_kernel(
    const unsigned short* __restrict__ act,
    const unsigned short* __restrict__ w2p,
    const int* __restrict__ cnt, const int* __restrict__ plist,
    float* __restrict__ out) {
  const int e = blockIdx.x >> 4;
  const int mt = blockIdx.x & 15;
  const int M = cnt[e];
  if (mt * 128 >= M) return;
  const int Mrem = M - mt * 128;
  const int nt = blockIdx.y;
  const int n0 = nt * 128;

  __shared__ __align__(16) unsigned short As[2][128][64];
  __shared__ __align__(16) unsigned short Bs[2][128][64];

  const int tid = threadIdx.x;
  const int lane = tid & 63;
  const int wid = tid >> 6;
  const int wm = (wid >> 1) * 64;
  const int wn = (wid & 1) * 64;

  const unsigned short* aSrc[4];
#pragma unroll
  for (int i = 0; i < 4; ++i) {
    int r = wid * 32 + i * 8 + (lane >> 3);
    int idx = mt * 128 + ((r < Mrem) ? r : 0);
    int p = plist[e * T_ + idx];
    aSrc[i] = act + (size_t)p * I_ + (lane & 7) * 8;
  }
  const unsigned short* bT = w2p + (size_t)((e * 8 + nt) * 32) * 8192;
  const unsigned short* bSrc[4];
#pragma unroll
  for (int i = 0; i < 4; ++i)
    bSrc[i] = bT + (wid * 32 + i * 8 + (lane >> 3)) * 64 + (lane & 7) * 8;

#define STAGE2(buf, kt)                                                       \
  do {                                                                        \
    _Pragma("unroll") for (int i = 0; i < 4; ++i) {                           \
      GLOAD_LDS16(aSrc[i] + (kt) * 64, &As[buf][wid * 32 + i * 8][0]);        \
      GLOAD_LDS16(bSrc[i] + (kt) * 8192, &Bs[buf][wid * 32 + i * 8][0]);      \
    }                                                                         \
  } while (0)

  f32x4 acc[4][4] = {};

  STAGE2(0, 0);
#pragma unroll 1
  for (int kt = 0; kt < 32; ++kt) {
    const int cur = kt & 1;
    if (kt + 1 < 32) {
      STAGE2(cur ^ 1, kt + 1);
      asm volatile("s_waitcnt vmcnt(8)" ::: "memory");
    } else {
      asm volatile("s_waitcnt vmcnt(0)" ::: "memory");
    }
    __builtin_amdgcn_s_barrier();
    __builtin_amdgcn_sched_barrier(0);
#pragma unroll
    for (int ks = 0; ks < 2; ++ks) {
      bf16x8 af[4], bfb[4];
#pragma unroll
      for (int mi = 0; mi < 4; ++mi)
        af[mi] = *(const bf16x8*)&As[cur][wm + mi * 16 + (lane & 15)][ks * 32 + (lane >> 4) * 8];
      const int cbase = ks * 4 + (lane >> 4);
#pragma unroll
      for (int ni = 0; ni < 4; ++ni) {
        int rr = wn + ni * 16 + (lane & 15);
        int cc = (cbase ^ (rr & 7)) << 3;
        bfb[ni] = *(const bf16x8*)&Bs[cur][rr][cc];
      }
#pragma unroll
      for (int mi = 0; mi < 4; ++mi)
#pragma unroll
        for (int ni = 0; ni < 4; ++ni)
          acc[mi][ni] = __builtin_amdgcn_mfma_f32_16x16x32_bf16(af[mi], bfb[ni], acc[mi][ni], 0, 0, 0);
    }
    __builtin_amdgcn_sched_barrier(0);
    __builtin_amdgcn_s_barrier();
  }

  const int lrow = lane >> 4, lcol = lane & 15;
#pragma unroll
  for (int mi = 0; mi < 4; ++mi) {
#pragma unroll
    for (int r = 0; r < 4; ++r) {
      int rl = wm + mi * 16 + lrow * 4 + r;
      if (rl < Mrem) {
        int p = plist[e * T_ + mt * 128 + rl];
        int t = p >> 1;
#pragma unroll
        for (int ni = 0; ni < 4; ++ni)
          atomicAdd(&out[(size_t)t * H_ + n0 + wn + ni * 16 + lcol], acc[mi][ni][r]);
      }
    }
  }
}

extern "C" void kernel_launch(void* const* d_in, const int* in_sizes, int n_in,
                              void* d_out, int out_size, void* d_ws, size_t ws_size,
                              hipStream_t stream) {
  const float* hs     = (const float*)d_in[0];
  const float* logits = (const float*)d_in[1];
  const float* w13    = (const float*)d_in[2];
  const float* w2     = (const float*)d_in[3];
  float* out = (float*)d_out;

  char* ws = (char*)d_ws;
  size_t off = 0;
  int* cnt = (int*)(ws + off);           off += 256;
  int* plist = (int*)(ws + off);         off += (size_t)E_ * T_ * 4;
  float* wlist = (float*)(ws + off);     off += (size_t)E_ * T_ * 4;
  unsigned short* act = (unsigned short*)(ws + off);   off += (size_t)2 * T_ * I_ * 2;
  unsigned short* hs_bf = (unsigned short*)(ws + off); off += (size_t)T_ * H_ * 2;
  unsigned short* w13p = (unsigned short*)(ws + off);  off += (size_t)E_ * 2 * I_ * H_ * 2;
  unsigned short* w2p = (unsigned short*)(ws + off);   off += (size_t)E_ * H_ * I_ * 2;
  // total ~116 MB

  hipMemsetAsync(cnt, 0, 256, stream);
  hipMemsetAsync(d_out, 0, (size_t)out_size * sizeof(float), stream);

  const int nHs = T_ * H_ / 8;
  cvt_kernel<<<(nHs + 255) / 256, 256, 0, stream>>>(hs, hs_bf, nHs);
  pack_w13<<<E_ * 32 * 16, 256, 0, stream>>>(w13, w13p);
  pack_w2<<<E_ * 8 * 32, 256, 0, stream>>>(w2, w2p);
  router_kernel<<<T_ / 256, 256, 0, stream>>>(logits, cnt, plist, wlist);

  gemm1_kernel<<<dim3(E_ * 16, I_ / 64), 256, 0, stream>>>(hs_bf, w13p, cnt, plist, wlist, act);
  gemm2_kernel<<<dim3(E_ * 16, H_ / 128), 256, 0, stream>>>(act, w2p, cnt, plist, out);
}

// Round 5
// 244.931 us; speedup vs baseline: 2.5125x; 1.4563x over previous
//
#include <hip/hip_runtime.h>

#define T_ 2048
#define H_ 1024
#define E_ 8
#define I_ 2048

typedef short bf16x8 __attribute__((ext_vector_type(8)));
typedef float f32x4 __attribute__((ext_vector_type(4)));
typedef unsigned short u16x8 __attribute__((ext_vector_type(8)));

__device__ __forceinline__ unsigned short f2bf(float f) {
  unsigned u = __builtin_bit_cast(unsigned, f);
  u += 0x7fffu + ((u >> 16) & 1u);   // RNE (finite inputs only)
  return (unsigned short)(u >> 16);
}

#define GLOAD_LDS16(g, l)                                                     \
  __builtin_amdgcn_global_load_lds(                                           \
      (const __attribute__((address_space(1))) unsigned int*)(g),             \
      (__attribute__((address_space(3))) unsigned int*)(l), 16, 0, 0)

// ---------------- fp32 -> bf16 linear convert (hs only) --------------------
__global__ __launch_bounds__(256) void cvt_kernel(const float* __restrict__ s,
                                                  unsigned short* __restrict__ d,
                                                  int n8) {
  int i = blockIdx.x * blockDim.x + threadIdx.x;
  if (i >= n8) return;
  const float4* s4 = (const float4*)s;
  float4 a = s4[2 * i], b = s4[2 * i + 1];
  u16x8 v;
  v[0] = f2bf(a.x); v[1] = f2bf(a.y); v[2] = f2bf(a.z); v[3] = f2bf(a.w);
  v[4] = f2bf(b.x); v[5] = f2bf(b.y); v[6] = f2bf(b.z); v[7] = f2bf(b.w);
  *(u16x8*)(d + (size_t)i * 8) = v;
}

// ---------------- router: softmax + top2 + expert compaction ----------------
__global__ void router_kernel(const float* __restrict__ logits,
                              int* __restrict__ cnt,
                              int* __restrict__ plist,
                              float* __restrict__ wlist) {
  int t = blockIdx.x * blockDim.x + threadIdx.x;
  if (t >= T_) return;
  float l[E_];
#pragma unroll
  for (int e = 0; e < E_; ++e) l[e] = logits[t * E_ + e];
  int i0 = 0;
#pragma unroll
  for (int e = 1; e < E_; ++e) if (l[e] > l[i0]) i0 = e;
  int i1 = (i0 == 0) ? 1 : 0;
#pragma unroll
  for (int e = 0; e < E_; ++e) if (e != i0 && l[e] > l[i1]) i1 = e;
  float w1 = 1.f / (1.f + __expf(l[i0] - l[i1]));
  float w0 = 1.f - w1;
  int s0 = atomicAdd(&cnt[i0], 1);
  plist[i0 * T_ + s0] = 2 * t;
  wlist[i0 * T_ + s0] = w0;
  int s1 = atomicAdd(&cnt[i1], 1);
  plist[i1 * T_ + s1] = 2 * t + 1;
  wlist[i1 * T_ + s1] = w1;
}

// ---------------- GEMM1: act = silu(hs*w13_g)*(hs*w13_u)*w ------------------
// BM=128, BN=64 i-cols (gate+up => 128 B rows), BK=32, 4 waves.
// A: bf16 gload_lds double-buffered (pre-swizzled source cols).
// B: fp32 reg-staged -> cvt -> swizzled ds_write, single buffer.
// grid 1D 4096: e=bid&7 (XCD pin), mt=(bid>>3)&15, nt=bid>>7.
__global__ __launch_bounds__(256, 4) void gemm1_kernel(
    const unsigned short* __restrict__ hs_bf,
    const float* __restrict__ w13,
    const int* __restrict__ cnt, const int* __restrict__ plist,
    const float* __restrict__ wlist, unsigned short* __restrict__ act) {
  const int bid = blockIdx.x;
  const int e = bid & 7;
  const int mt = (bid >> 3) & 15;
  const int nt = bid >> 7;                 // 0..31
  const int M = cnt[e];
  if (mt * 128 >= M) return;
  const int Mrem = M - mt * 128;
  const int n0 = nt * 64;

  __shared__ __align__(16) unsigned short As[2][128][32];
  __shared__ __align__(16) unsigned short Bs[128][32];

  const int tid = threadIdx.x;
  const int lane = tid & 63;
  const int wid = tid >> 6;
  const int wm = (wid >> 1) * 64;
  const int wn = (wid & 1) * 32;

  // A staging sources: row = wid*32 + i*16 + (lane>>2), source col XOR-preswizzled
  const unsigned short* aSrc0;
  const unsigned short* aSrc1;
  {
    int cg = ((lane & 3) ^ ((lane >> 3) & 3)) * 8;
#pragma unroll
    for (int i = 0; i < 2; ++i) {
      int r = wid * 32 + i * 16 + (lane >> 2);
      int idx = mt * 128 + ((r < Mrem) ? r : 0);
      int p = plist[e * T_ + idx];
      const unsigned short* s = hs_bf + (size_t)(p >> 1) * H_ + cg;
      if (i == 0) aSrc0 = s; else aSrc1 = s;
    }
  }
  // B staging: row rb = wid*32 + (lane>>1); 16 f32 per lane at col (lane&1)*16
  const int rb = wid * 32 + (lane >> 1);
  const int wrow = (rb < 64) ? (e * 2 * I_ + n0 + rb)
                             : (e * 2 * I_ + I_ + n0 + (rb - 64));
  const float* bSrc = w13 + (size_t)wrow * H_ + (lane & 1) * 16;
  const int fb = (rb >> 1) & 3;
  unsigned short* bDst0 = &Bs[rb][((((lane & 1) << 1) | 0) ^ fb) * 8];
  unsigned short* bDst1 = &Bs[rb][((((lane & 1) << 1) | 1) ^ fb) * 8];

  const int rda = ((lane >> 4) ^ ((lane >> 1) & 3)) * 8;  // frag col (A & B)
  const int l15 = lane & 15;

  f32x4 accg[4][2] = {};
  f32x4 accu[4][2] = {};

  // prologue: issue A(0), B(0)
  GLOAD_LDS16(aSrc0, &As[0][wid * 32][0]);
  GLOAD_LDS16(aSrc1, &As[0][wid * 32 + 16][0]);
  float4 b0 = *(const float4*)(bSrc + 0);
  float4 b1 = *(const float4*)(bSrc + 4);
  float4 b2 = *(const float4*)(bSrc + 8);
  float4 b3 = *(const float4*)(bSrc + 12);

#pragma unroll 1
  for (int kt = 0; kt < 32; ++kt) {
    const int cur = kt & 1;
    asm volatile("s_waitcnt vmcnt(0)" ::: "memory");
    // convert + write B(kt)
    {
      u16x8 lo, hi;
      lo[0] = f2bf(b0.x); lo[1] = f2bf(b0.y); lo[2] = f2bf(b0.z); lo[3] = f2bf(b0.w);
      lo[4] = f2bf(b1.x); lo[5] = f2bf(b1.y); lo[6] = f2bf(b1.z); lo[7] = f2bf(b1.w);
      hi[0] = f2bf(b2.x); hi[1] = f2bf(b2.y); hi[2] = f2bf(b2.z); hi[3] = f2bf(b2.w);
      hi[4] = f2bf(b3.x); hi[5] = f2bf(b3.y); hi[6] = f2bf(b3.z); hi[7] = f2bf(b3.w);
      *(u16x8*)bDst0 = lo;
      *(u16x8*)bDst1 = hi;
    }
    // issue next-tile loads (land during this tile's compute)
    if (kt + 1 < 32) {
      GLOAD_LDS16(aSrc0 + (kt + 1) * 32, &As[cur ^ 1][wid * 32][0]);
      GLOAD_LDS16(aSrc1 + (kt + 1) * 32, &As[cur ^ 1][wid * 32 + 16][0]);
      b0 = *(const float4*)(bSrc + (kt + 1) * 32 + 0);
      b1 = *(const float4*)(bSrc + (kt + 1) * 32 + 4);
      b2 = *(const float4*)(bSrc + (kt + 1) * 32 + 8);
      b3 = *(const float4*)(bSrc + (kt + 1) * 32 + 12);
    }
    asm volatile("s_waitcnt lgkmcnt(0)" ::: "memory");
    __builtin_amdgcn_s_barrier();
    __builtin_amdgcn_sched_barrier(0);

    bf16x8 bg[2], bu[2];
#pragma unroll
    for (int ni = 0; ni < 2; ++ni) {
      bg[ni] = *(const bf16x8*)&Bs[wn + ni * 16 + l15][rda];
      bu[ni] = *(const bf16x8*)&Bs[64 + wn + ni * 16 + l15][rda];
    }
#pragma unroll
    for (int mi = 0; mi < 4; ++mi) {
      bf16x8 af = *(const bf16x8*)&As[cur][wm + mi * 16 + l15][rda];
#pragma unroll
      for (int ni = 0; ni < 2; ++ni) {
        accg[mi][ni] = __builtin_amdgcn_mfma_f32_16x16x32_bf16(af, bg[ni], accg[mi][ni], 0, 0, 0);
        accu[mi][ni] = __builtin_amdgcn_mfma_f32_16x16x32_bf16(af, bu[ni], accu[mi][ni], 0, 0, 0);
      }
    }
    __builtin_amdgcn_sched_barrier(0);
    __builtin_amdgcn_s_barrier();
  }

  const int lrow = lane >> 4, lcol = lane & 15;
#pragma unroll
  for (int mi = 0; mi < 4; ++mi) {
#pragma unroll
    for (int r = 0; r < 4; ++r) {
      int rl = wm + mi * 16 + lrow * 4 + r;
      if (rl < Mrem) {
        int rr = mt * 128 + rl;
        int p = plist[e * T_ + rr];
        float w = wlist[e * T_ + rr];
        unsigned short* dst = act + (size_t)p * I_ + n0;
#pragma unroll
        for (int ni = 0; ni < 2; ++ni) {
          float g = accg[mi][ni][r];
          float u = accu[mi][ni][r];
          float a = (g / (1.f + __expf(-g))) * u * w;
          dst[wn + ni * 16 + lcol] = f2bf(a);
        }
      }
    }
  }
}

// ---------------- GEMM2: out[t,h] += act[p,:] . w2[e,h,:] -------------------
// BM=128, BN=128 h-cols, BK=32, same structure. grid 1024: e=bid&7.
__global__ __launch_bounds__(256, 4) void gemm2_kernel(
    const unsigned short* __restrict__ act,
    const float* __restrict__ w2,
    const int* __restrict__ cnt, const int* __restrict__ plist,
    float* __restrict__ out) {
  const int bid = blockIdx.x;
  const int e = bid & 7;
  const int mt = (bid >> 3) & 15;
  const int nt = bid >> 7;                 // 0..7
  const int M = cnt[e];
  if (mt * 128 >= M) return;
  const int Mrem = M - mt * 128;
  const int n0 = nt * 128;

  __shared__ __align__(16) unsigned short As[2][128][32];
  __shared__ __align__(16) unsigned short Bs[128][32];

  const int tid = threadIdx.x;
  const int lane = tid & 63;
  const int wid = tid >> 6;
  const int wm = (wid >> 1) * 64;
  const int wn = (wid & 1) * 64;

  const unsigned short* aSrc0;
  const unsigned short* aSrc1;
  {
    int cg = ((lane & 3) ^ ((lane >> 3) & 3)) * 8;
#pragma unroll
    for (int i = 0; i < 2; ++i) {
      int r = wid * 32 + i * 16 + (lane >> 2);
      int idx = mt * 128 + ((r < Mrem) ? r : 0);
      int p = plist[e * T_ + idx];
      const unsigned short* s = act + (size_t)p * I_ + cg;
      if (i == 0) aSrc0 = s; else aSrc1 = s;
    }
  }
  const int rb = wid * 32 + (lane >> 1);
  const float* bSrc = w2 + ((size_t)e * H_ + n0 + rb) * I_ + (lane & 1) * 16;
  const int fb = (rb >> 1) & 3;
  unsigned short* bDst0 = &Bs[rb][((((lane & 1) << 1) | 0) ^ fb) * 8];
  unsigned short* bDst1 = &Bs[rb][((((lane & 1) << 1) | 1) ^ fb) * 8];

  const int rda = ((lane >> 4) ^ ((lane >> 1) & 3)) * 8;
  const int l15 = lane & 15;

  f32x4 acc[4][4] = {};

  GLOAD_LDS16(aSrc0, &As[0][wid * 32][0]);
  GLOAD_LDS16(aSrc1, &As[0][wid * 32 + 16][0]);
  float4 b0 = *(const float4*)(bSrc + 0);
  float4 b1 = *(const float4*)(bSrc + 4);
  float4 b2 = *(const float4*)(bSrc + 8);
  float4 b3 = *(const float4*)(bSrc + 12);

#pragma unroll 1
  for (int kt = 0; kt < 64; ++kt) {
    const int cur = kt & 1;
    asm volatile("s_waitcnt vmcnt(0)" ::: "memory");
    {
      u16x8 lo, hi;
      lo[0] = f2bf(b0.x); lo[1] = f2bf(b0.y); lo[2] = f2bf(b0.z); lo[3] = f2bf(b0.w);
      lo[4] = f2bf(b1.x); lo[5] = f2bf(b1.y); lo[6] = f2bf(b1.z); lo[7] = f2bf(b1.w);
      hi[0] = f2bf(b2.x); hi[1] = f2bf(b2.y); hi[2] = f2bf(b2.z); hi[3] = f2bf(b2.w);
      hi[4] = f2bf(b3.x); hi[5] = f2bf(b3.y); hi[6] = f2bf(b3.z); hi[7] = f2bf(b3.w);
      *(u16x8*)bDst0 = lo;
      *(u16x8*)bDst1 = hi;
    }
    if (kt + 1 < 64) {
      GLOAD_LDS16(aSrc0 + (kt + 1) * 32, &As[cur ^ 1][wid * 32][0]);
      GLOAD_LDS16(aSrc1 + (kt + 1) * 32, &As[cur ^ 1][wid * 32 + 16][0]);
      b0 = *(const float4*)(bSrc + (kt + 1) * 32 + 0);
      b1 = *(const float4*)(bSrc + (kt + 1) * 32 + 4);
      b2 = *(const float4*)(bSrc + (kt + 1) * 32 + 8);
      b3 = *(const float4*)(bSrc + (kt + 1) * 32 + 12);
    }
    asm volatile("s_waitcnt lgkmcnt(0)" ::: "memory");
    __builtin_amdgcn_s_barrier();
    __builtin_amdgcn_sched_barrier(0);

    bf16x8 bb[4];
#pragma unroll
    for (int ni = 0; ni < 4; ++ni)
      bb[ni] = *(const bf16x8*)&Bs[wn + ni * 16 + l15][rda];
#pragma unroll
    for (int mi = 0; mi < 4; ++mi) {
      bf16x8 af = *(const bf16x8*)&As[cur][wm + mi * 16 + l15][rda];
#pragma unroll
      for (int ni = 0; ni < 4; ++ni)
        acc[mi][ni] = __builtin_amdgcn_mfma_f32_16x16x32_bf16(af, bb[ni], acc[mi][ni], 0, 0, 0);
    }
    __builtin_amdgcn_sched_barrier(0);
    __builtin_amdgcn_s_barrier();
  }

  const int lrow = lane >> 4, lcol = lane & 15;
#pragma unroll
  for (int mi = 0; mi < 4; ++mi) {
#pragma unroll
    for (int r = 0; r < 4; ++r) {
      int rl = wm + mi * 16 + lrow * 4 + r;
      if (rl < Mrem) {
        int p = plist[e * T_ + mt * 128 + rl];
        int t = p >> 1;
#pragma unroll
        for (int ni = 0; ni < 4; ++ni)
          atomicAdd(&out[(size_t)t * H_ + n0 + wn + ni * 16 + lcol], acc[mi][ni][r]);
      }
    }
  }
}

extern "C" void kernel_launch(void* const* d_in, const int* in_sizes, int n_in,
                              void* d_out, int out_size, void* d_ws, size_t ws_size,
                              hipStream_t stream) {
  const float* hs     = (const float*)d_in[0];
  const float* logits = (const float*)d_in[1];
  const float* w13    = (const float*)d_in[2];
  const float* w2     = (const float*)d_in[3];
  float* out = (float*)d_out;

  char* ws = (char*)d_ws;
  size_t off = 0;
  int* cnt = (int*)(ws + off);           off += 256;
  int* plist = (int*)(ws + off);         off += (size_t)E_ * T_ * 4;
  float* wlist = (float*)(ws + off);     off += (size_t)E_ * T_ * 4;
  unsigned short* act = (unsigned short*)(ws + off);   off += (size_t)2 * T_ * I_ * 2;
  unsigned short* hs_bf = (unsigned short*)(ws + off); off += (size_t)T_ * H_ * 2;
  // total ~20.3 MB

  hipMemsetAsync(cnt, 0, 256, stream);
  hipMemsetAsync(d_out, 0, (size_t)out_size * sizeof(float), stream);

  const int nHs = T_ * H_ / 8;
  cvt_kernel<<<(nHs + 255) / 256, 256, 0, stream>>>(hs, hs_bf, nHs);
  router_kernel<<<T_ / 256, 256, 0, stream>>>(logits, cnt, plist, wlist);

  gemm1_kernel<<<E_ * 16 * 32, 256, 0, stream>>>(hs_bf, w13, cnt, plist, wlist, act);
  gemm2_kernel<<<E_ * 16 * 8, 256, 0, stream>>>(act, w2, cnt, plist, out);
}

// Round 6
// 216.961 us; speedup vs baseline: 2.8364x; 1.1289x over previous
//
#include <hip/hip_runtime.h>

#define T_ 2048
#define H_ 1024
#define E_ 8
#define I_ 2048

typedef short bf16x8 __attribute__((ext_vector_type(8)));
typedef float f32x4 __attribute__((ext_vector_type(4)));
typedef unsigned short u16x8 __attribute__((ext_vector_type(8)));

__device__ __forceinline__ unsigned short f2bf(float f) {
  unsigned u = __builtin_bit_cast(unsigned, f);
  u += 0x7fffu + ((u >> 16) & 1u);   // RNE (finite inputs only)
  return (unsigned short)(u >> 16);
}

#define GLOAD_LDS16(g, l)                                                     \
  __builtin_amdgcn_global_load_lds(                                           \
      (const __attribute__((address_space(1))) unsigned int*)(g),             \
      (__attribute__((address_space(3))) unsigned int*)(l), 16, 0, 0)

// ---------------- fp32 -> bf16 linear convert (hs only) --------------------
__global__ __launch_bounds__(256) void cvt_kernel(const float* __restrict__ s,
                                                  unsigned short* __restrict__ d,
                                                  int n8) {
  int i = blockIdx.x * blockDim.x + threadIdx.x;
  if (i >= n8) return;
  const float4* s4 = (const float4*)s;
  float4 a = s4[2 * i], b = s4[2 * i + 1];
  u16x8 v;
  v[0] = f2bf(a.x); v[1] = f2bf(a.y); v[2] = f2bf(a.z); v[3] = f2bf(a.w);
  v[4] = f2bf(b.x); v[5] = f2bf(b.y); v[6] = f2bf(b.z); v[7] = f2bf(b.w);
  *(u16x8*)(d + (size_t)i * 8) = v;
}

// ---------------- router: softmax + top2 + expert compaction ----------------
__global__ void router_kernel(const float* __restrict__ logits,
                              int* __restrict__ cnt,
                              int* __restrict__ plist,
                              float* __restrict__ wlist) {
  int t = blockIdx.x * blockDim.x + threadIdx.x;
  if (t >= T_) return;
  float l[E_];
#pragma unroll
  for (int e = 0; e < E_; ++e) l[e] = logits[t * E_ + e];
  int i0 = 0;
#pragma unroll
  for (int e = 1; e < E_; ++e) if (l[e] > l[i0]) i0 = e;
  int i1 = (i0 == 0) ? 1 : 0;
#pragma unroll
  for (int e = 0; e < E_; ++e) if (e != i0 && l[e] > l[i1]) i1 = e;
  float w1 = 1.f / (1.f + __expf(l[i0] - l[i1]));
  float w0 = 1.f - w1;
  int s0 = atomicAdd(&cnt[i0], 1);
  plist[i0 * T_ + s0] = 2 * t;
  wlist[i0 * T_ + s0] = w0;
  int s1 = atomicAdd(&cnt[i1], 1);
  plist[i1 * T_ + s1] = 2 * t + 1;
  wlist[i1 * T_ + s1] = w1;
}

// ---------------- GEMM1: act = silu(hs*w13_g)*(hs*w13_u)*w ------------------
// BM=128, BN=64 i-cols (gate+up => 128 B rows), BK=32, 4 waves.
// A: bf16 gload_lds double-buffered (pre-swizzled source cols).
// B: fp32 reg-staged -> cvt -> swizzled ds_write, single buffer.
// grid 1D 4096: e=bid&7 (XCD pin), mt=(bid>>3)&15, nt=bid>>7.
__global__ __launch_bounds__(256, 4) void gemm1_kernel(
    const unsigned short* __restrict__ hs_bf,
    const float* __restrict__ w13,
    const int* __restrict__ cnt, const int* __restrict__ plist,
    const float* __restrict__ wlist, unsigned short* __restrict__ act) {
  const int bid = blockIdx.x;
  const int e = bid & 7;
  const int mt = (bid >> 3) & 15;
  const int nt = bid >> 7;                 // 0..31
  const int M = cnt[e];
  if (mt * 128 >= M) return;
  const int Mrem = M - mt * 128;
  const int n0 = nt * 64;

  __shared__ __align__(16) unsigned short As[2][128][32];
  __shared__ __align__(16) unsigned short Bs[128][32];

  const int tid = threadIdx.x;
  const int lane = tid & 63;
  const int wid = tid >> 6;
  const int wm = (wid >> 1) * 64;
  const int wn = (wid & 1) * 32;

  const unsigned short* aSrc0;
  const unsigned short* aSrc1;
  {
    int cg = ((lane & 3) ^ ((lane >> 3) & 3)) * 8;
#pragma unroll
    for (int i = 0; i < 2; ++i) {
      int r = wid * 32 + i * 16 + (lane >> 2);
      int idx = mt * 128 + ((r < Mrem) ? r : 0);
      int p = plist[e * T_ + idx];
      const unsigned short* s = hs_bf + (size_t)(p >> 1) * H_ + cg;
      if (i == 0) aSrc0 = s; else aSrc1 = s;
    }
  }
  const int rb = wid * 32 + (lane >> 1);
  const int wrow = (rb < 64) ? (e * 2 * I_ + n0 + rb)
                             : (e * 2 * I_ + I_ + n0 + (rb - 64));
  const float* bSrc = w13 + (size_t)wrow * H_ + (lane & 1) * 16;
  const int fb = (rb >> 1) & 3;
  unsigned short* bDst0 = &Bs[rb][((((lane & 1) << 1) | 0) ^ fb) * 8];
  unsigned short* bDst1 = &Bs[rb][((((lane & 1) << 1) | 1) ^ fb) * 8];

  const int rda = ((lane >> 4) ^ ((lane >> 1) & 3)) * 8;  // frag col (A & B)
  const int l15 = lane & 15;

  f32x4 accg[4][2] = {};
  f32x4 accu[4][2] = {};

  GLOAD_LDS16(aSrc0, &As[0][wid * 32][0]);
  GLOAD_LDS16(aSrc1, &As[0][wid * 32 + 16][0]);
  float4 b0 = *(const float4*)(bSrc + 0);
  float4 b1 = *(const float4*)(bSrc + 4);
  float4 b2 = *(const float4*)(bSrc + 8);
  float4 b3 = *(const float4*)(bSrc + 12);

#pragma unroll 1
  for (int kt = 0; kt < 32; ++kt) {
    const int cur = kt & 1;
    asm volatile("s_waitcnt vmcnt(0)" ::: "memory");
    {
      u16x8 lo, hi;
      lo[0] = f2bf(b0.x); lo[1] = f2bf(b0.y); lo[2] = f2bf(b0.z); lo[3] = f2bf(b0.w);
      lo[4] = f2bf(b1.x); lo[5] = f2bf(b1.y); lo[6] = f2bf(b1.z); lo[7] = f2bf(b1.w);
      hi[0] = f2bf(b2.x); hi[1] = f2bf(b2.y); hi[2] = f2bf(b2.z); hi[3] = f2bf(b2.w);
      hi[4] = f2bf(b3.x); hi[5] = f2bf(b3.y); hi[6] = f2bf(b3.z); hi[7] = f2bf(b3.w);
      *(u16x8*)bDst0 = lo;
      *(u16x8*)bDst1 = hi;
    }
    if (kt + 1 < 32) {
      GLOAD_LDS16(aSrc0 + (kt + 1) * 32, &As[cur ^ 1][wid * 32][0]);
      GLOAD_LDS16(aSrc1 + (kt + 1) * 32, &As[cur ^ 1][wid * 32 + 16][0]);
      b0 = *(const float4*)(bSrc + (kt + 1) * 32 + 0);
      b1 = *(const float4*)(bSrc + (kt + 1) * 32 + 4);
      b2 = *(const float4*)(bSrc + (kt + 1) * 32 + 8);
      b3 = *(const float4*)(bSrc + (kt + 1) * 32 + 12);
    }
    asm volatile("s_waitcnt lgkmcnt(0)" ::: "memory");
    __builtin_amdgcn_s_barrier();
    __builtin_amdgcn_sched_barrier(0);

    bf16x8 bg[2], bu[2];
#pragma unroll
    for (int ni = 0; ni < 2; ++ni) {
      bg[ni] = *(const bf16x8*)&Bs[wn + ni * 16 + l15][rda];
      bu[ni] = *(const bf16x8*)&Bs[64 + wn + ni * 16 + l15][rda];
    }
#pragma unroll
    for (int mi = 0; mi < 4; ++mi) {
      bf16x8 af = *(const bf16x8*)&As[cur][wm + mi * 16 + l15][rda];
#pragma unroll
      for (int ni = 0; ni < 2; ++ni) {
        accg[mi][ni] = __builtin_amdgcn_mfma_f32_16x16x32_bf16(af, bg[ni], accg[mi][ni], 0, 0, 0);
        accu[mi][ni] = __builtin_amdgcn_mfma_f32_16x16x32_bf16(af, bu[ni], accu[mi][ni], 0, 0, 0);
      }
    }
    __builtin_amdgcn_sched_barrier(0);
    __builtin_amdgcn_s_barrier();
  }

  const int lrow = lane >> 4, lcol = lane & 15;
#pragma unroll
  for (int mi = 0; mi < 4; ++mi) {
#pragma unroll
    for (int r = 0; r < 4; ++r) {
      int rl = wm + mi * 16 + lrow * 4 + r;
      if (rl < Mrem) {
        int rr = mt * 128 + rl;
        int p = plist[e * T_ + rr];
        float w = wlist[e * T_ + rr];
        unsigned short* dst = act + (size_t)p * I_ + n0;
#pragma unroll
        for (int ni = 0; ni < 2; ++ni) {
          float g = accg[mi][ni][r];
          float u = accu[mi][ni][r];
          float a = (g / (1.f + __expf(-g))) * u * w;
          dst[wn + ni * 16 + lcol] = f2bf(a);
        }
      }
    }
  }
}

// ---------------- GEMM2: out[t,h] += act[p,:] . w2[e,h,:] -------------------
// BM=128, BN=128 h-cols, BK=32, K-split x4 (512-wide chunks), atomic out.
// grid 4096: e=bid&7 (XCD pin), mt=(bid>>3)&15, nt=(bid>>7)&7, kb=bid>>10.
__global__ __launch_bounds__(256, 4) void gemm2_kernel(
    const unsigned short* __restrict__ act,
    const float* __restrict__ w2,
    const int* __restrict__ cnt, const int* __restrict__ plist,
    float* __restrict__ out) {
  const int bid = blockIdx.x;
  const int e = bid & 7;
  const int mt = (bid >> 3) & 15;
  const int nt = (bid >> 7) & 7;
  const int kb = bid >> 10;                // 0..3, K chunk of 512
  const int M = cnt[e];
  if (mt * 128 >= M) return;
  const int Mrem = M - mt * 128;
  const int n0 = nt * 128;
  const int k0 = kb * 512;

  __shared__ __align__(16) unsigned short As[2][128][32];
  __shared__ __align__(16) unsigned short Bs[128][32];

  const int tid = threadIdx.x;
  const int lane = tid & 63;
  const int wid = tid >> 6;
  const int wm = (wid >> 1) * 64;
  const int wn = (wid & 1) * 64;

  const unsigned short* aSrc0;
  const unsigned short* aSrc1;
  {
    int cg = ((lane & 3) ^ ((lane >> 3) & 3)) * 8;
#pragma unroll
    for (int i = 0; i < 2; ++i) {
      int r = wid * 32 + i * 16 + (lane >> 2);
      int idx = mt * 128 + ((r < Mrem) ? r : 0);
      int p = plist[e * T_ + idx];
      const unsigned short* s = act + (size_t)p * I_ + k0 + cg;
      if (i == 0) aSrc0 = s; else aSrc1 = s;
    }
  }
  const int rb = wid * 32 + (lane >> 1);
  const float* bSrc = w2 + ((size_t)e * H_ + n0 + rb) * I_ + k0 + (lane & 1) * 16;
  const int fb = (rb >> 1) & 3;
  unsigned short* bDst0 = &Bs[rb][((((lane & 1) << 1) | 0) ^ fb) * 8];
  unsigned short* bDst1 = &Bs[rb][((((lane & 1) << 1) | 1) ^ fb) * 8];

  const int rda = ((lane >> 4) ^ ((lane >> 1) & 3)) * 8;
  const int l15 = lane & 15;

  f32x4 acc[4][4] = {};

  GLOAD_LDS16(aSrc0, &As[0][wid * 32][0]);
  GLOAD_LDS16(aSrc1, &As[0][wid * 32 + 16][0]);
  float4 b0 = *(const float4*)(bSrc + 0);
  float4 b1 = *(const float4*)(bSrc + 4);
  float4 b2 = *(const float4*)(bSrc + 8);
  float4 b3 = *(const float4*)(bSrc + 12);

#pragma unroll 1
  for (int kt = 0; kt < 16; ++kt) {
    const int cur = kt & 1;
    asm volatile("s_waitcnt vmcnt(0)" ::: "memory");
    {
      u16x8 lo, hi;
      lo[0] = f2bf(b0.x); lo[1] = f2bf(b0.y); lo[2] = f2bf(b0.z); lo[3] = f2bf(b0.w);
      lo[4] = f2bf(b1.x); lo[5] = f2bf(b1.y); lo[6] = f2bf(b1.z); lo[7] = f2bf(b1.w);
      hi[0] = f2bf(b2.x); hi[1] = f2bf(b2.y); hi[2] = f2bf(b2.z); hi[3] = f2bf(b2.w);
      hi[4] = f2bf(b3.x); hi[5] = f2bf(b3.y); hi[6] = f2bf(b3.z); hi[7] = f2bf(b3.w);
      *(u16x8*)bDst0 = lo;
      *(u16x8*)bDst1 = hi;
    }
    if (kt + 1 < 16) {
      GLOAD_LDS16(aSrc0 + (kt + 1) * 32, &As[cur ^ 1][wid * 32][0]);
      GLOAD_LDS16(aSrc1 + (kt + 1) * 32, &As[cur ^ 1][wid * 32 + 16][0]);
      b0 = *(const float4*)(bSrc + (kt + 1) * 32 + 0);
      b1 = *(const float4*)(bSrc + (kt + 1) * 32 + 4);
      b2 = *(const float4*)(bSrc + (kt + 1) * 32 + 8);
      b3 = *(const float4*)(bSrc + (kt + 1) * 32 + 12);
    }
    asm volatile("s_waitcnt lgkmcnt(0)" ::: "memory");
    __builtin_amdgcn_s_barrier();
    __builtin_amdgcn_sched_barrier(0);

    bf16x8 bb[4];
#pragma unroll
    for (int ni = 0; ni < 4; ++ni)
      bb[ni] = *(const bf16x8*)&Bs[wn + ni * 16 + l15][rda];
#pragma unroll
    for (int mi = 0; mi < 4; ++mi) {
      bf16x8 af = *(const bf16x8*)&As[cur][wm + mi * 16 + l15][rda];
#pragma unroll
      for (int ni = 0; ni < 4; ++ni)
        acc[mi][ni] = __builtin_amdgcn_mfma_f32_16x16x32_bf16(af, bb[ni], acc[mi][ni], 0, 0, 0);
    }
    __builtin_amdgcn_sched_barrier(0);
    __builtin_amdgcn_s_barrier();
  }

  const int lrow = lane >> 4, lcol = lane & 15;
#pragma unroll
  for (int mi = 0; mi < 4; ++mi) {
#pragma unroll
    for (int r = 0; r < 4; ++r) {
      int rl = wm + mi * 16 + lrow * 4 + r;
      if (rl < Mrem) {
        int p = plist[e * T_ + mt * 128 + rl];
        int t = p >> 1;
#pragma unroll
        for (int ni = 0; ni < 4; ++ni)
          atomicAdd(&out[(size_t)t * H_ + n0 + wn + ni * 16 + lcol], acc[mi][ni][r]);
      }
    }
  }
}

extern "C" void kernel_launch(void* const* d_in, const int* in_sizes, int n_in,
                              void* d_out, int out_size, void* d_ws, size_t ws_size,
                              hipStream_t stream) {
  const float* hs     = (const float*)d_in[0];
  const float* logits = (const float*)d_in[1];
  const float* w13    = (const float*)d_in[2];
  const float* w2     = (const float*)d_in[3];
  float* out = (float*)d_out;

  char* ws = (char*)d_ws;
  size_t off = 0;
  int* cnt = (int*)(ws + off);           off += 256;
  int* plist = (int*)(ws + off);         off += (size_t)E_ * T_ * 4;
  float* wlist = (float*)(ws + off);     off += (size_t)E_ * T_ * 4;
  unsigned short* act = (unsigned short*)(ws + off);   off += (size_t)2 * T_ * I_ * 2;
  unsigned short* hs_bf = (unsigned short*)(ws + off); off += (size_t)T_ * H_ * 2;
  // total ~20.3 MB

  hipMemsetAsync(cnt, 0, 256, stream);
  hipMemsetAsync(d_out, 0, (size_t)out_size * sizeof(float), stream);

  const int nHs = T_ * H_ / 8;
  cvt_kernel<<<(nHs + 255) / 256, 256, 0, stream>>>(hs, hs_bf, nHs);
  router_kernel<<<T_ / 256, 256, 0, stream>>>(logits, cnt, plist, wlist);

  gemm1_kernel<<<E_ * 16 * 32, 256, 0, stream>>>(hs_bf, w13, cnt, plist, wlist, act);
  gemm2_kernel<<<E_ * 16 * 8 * 4, 256, 0, stream>>>(act, w2, cnt, plist, out);
}